// Round 3
// baseline (140.485 us; speedup 1.0000x reference)
//
#include <hip/hip_runtime.h>
#include <hip/hip_bf16.h>

#define BB   2
#define TT   512
#define NF   6
#define DD   32
#define HIDD 128
#define NHH  4
#define HDD  32
#define GHH  32
#define FDD  128
#define LL   (TT*NF)      // 3072
#define EPSF 1e-5f
#define NQT16 (LL/16)     // 192

// R16: split-K geometry compile-time (NCH=16 regressed — reverted to 8).
#define NCHC 8
#define CCH  384          // keys per chunk = 6 tiles of 64
#define VPAD 8            // ldsV row padding (elems) — breaks stride-768B banks

// R17: gate_qkv tokens per block (was 4) — 4x weight-read amortization.
#define TPB  16

typedef __attribute__((ext_vector_type(8))) short  bf16x8;
typedef __attribute__((ext_vector_type(4))) float  f32x4;

#define MFMA16x16x32(a,b,c) __builtin_amdgcn_mfma_f32_16x16x32_bf16(a,b,c,0,0,0)

__device__ __forceinline__ unsigned short bfh(float f) {
    union { __hip_bfloat16 b; unsigned short u; } cv;
    cv.b = __float2bfloat16(f);
    return cv.u;
}
__device__ __forceinline__ float bff(unsigned short u) {
    return __uint_as_float(((unsigned)u) << 16);
}
__device__ __forceinline__ unsigned pk_bf16(float a, float b) {
    union { __hip_bfloat162 h2; unsigned u; } cv;
    cv.h2 = __float22bfloat162_rn(make_float2(a, b));
    return cv.u;
}
__device__ __forceinline__ bf16x8 ld8(const unsigned short* p) {
    return *reinterpret_cast<const bf16x8*>(p);
}

// exp2-domain softmax (log2e folded into Q scale) — R15, kept.
__device__ __forceinline__ float fexp2(float x) {
#if __has_builtin(__builtin_amdgcn_exp2f)
    return __builtin_amdgcn_exp2f(x);
#else
    return exp2f(x);
#endif
}

// 8 frags per 64-key tile (K-lo / V-lo splits dropped — R13/R14 verified).
struct Frags {
    bf16x8 k0, k1;   // keys X = [j0, j0+32), frag rows 0/1
    bf16x8 k2, k3;   // keys Y = [j0+32, j0+64)
    bf16x8 v0, v1, v2, v3;   // V^T hi: (dims rr / rr+16) x (X / Y)
};

// R16: frags come from LDS (latency-immune) instead of global/L2.
__device__ __forceinline__ void load_tile_lds(
    const unsigned short* ldsK, const unsigned short* ldsV,
    int j0loc, int kloc0, int kloc1, int quad, int rr, Frags& f)
{
    const int kX0 = (j0loc + kloc0) * HDD + quad * 8;
    const int kX1 = (j0loc + kloc1) * HDD + quad * 8;
    f.k0 = ld8(ldsK + kX0);
    f.k1 = ld8(ldsK + kX1);
    f.k2 = ld8(ldsK + kX0 + 32 * HDD);
    f.k3 = ld8(ldsK + kX1 + 32 * HDD);
    const int vX = j0loc + quad * 8, vY = vX + 32;
    const int vr0 = rr * (CCH + VPAD), vr1 = (rr + 16) * (CCH + VPAD);
    f.v0 = ld8(ldsV + vr0 + vX);
    f.v1 = ld8(ldsV + vr1 + vX);
    f.v2 = ld8(ldsV + vr0 + vY);
    f.v3 = ld8(ldsV + vr1 + vY);
}

// One tile's scores + online softmax + PV, updating (m, l, o0, o1).
// Scores/m are in log2 units (Q pre-scaled by log2e/sqrt(HD)).
// R17: DEFER-MAX (T13) — wave-uniform __all(lanemax - m <= 8) skips the
// cross-quad shfl reduce + corr exp2 + 9-mul rescale on tiles whose max
// doesn't grow. P values then bounded by 2^8; f32 l/o absorb it; the stored
// m stays consistent with its l/o so the merge is unchanged.
__device__ __forceinline__ void compute_tile(
    const Frags& f, const bf16x8 qfh, const bf16x8 qfl,
    int j0, int jminw, int jend, int quad,
    float& m, float& l, f32x4& o0, f32x4& o1)
{
    const f32x4 z = {0.f, 0.f, 0.f, 0.f};
    f32x4 s0 = MFMA16x16x32(f.k0, qfh, z);
    f32x4 s1 = MFMA16x16x32(f.k1, qfh, z);
    f32x4 s2 = MFMA16x16x32(f.k2, qfh, z);
    f32x4 s3 = MFMA16x16x32(f.k3, qfh, z);
    s0 = MFMA16x16x32(f.k0, qfl, s0);
    s1 = MFMA16x16x32(f.k1, qfl, s1);
    s2 = MFMA16x16x32(f.k2, qfl, s2);
    s3 = MFMA16x16x32(f.k3, qfl, s3);

    const bool interior = (j0 + 64 <= jminw);   // wave-uniform
    const int  je = jend - j0;
    const int  k0 = 8 * quad;

    float t16[16];
    if (interior) {
        #pragma unroll
        for (int r2 = 0; r2 < 4; r2++) {
            t16[r2]      = s0[r2];
            t16[4 + r2]  = s1[r2];
            t16[8 + r2]  = s2[r2];
            t16[12 + r2] = s3[r2];
        }
    } else {
        #pragma unroll
        for (int r2 = 0; r2 < 4; r2++) {
            t16[r2]      = (k0 + r2          < je) ? s0[r2] : -1e30f;
            t16[4 + r2]  = (k0 + 4 + r2      < je) ? s1[r2] : -1e30f;
            t16[8 + r2]  = (32 + k0 + r2     < je) ? s2[r2] : -1e30f;
            t16[12 + r2] = (32 + k0 + 4 + r2 < je) ? s3[r2] : -1e30f;
        }
    }

    // lane-local max (15 ops)
    float lanemax = t16[0];
    #pragma unroll
    for (int i = 1; i < 16; i++) lanemax = fmaxf(lanemax, t16[i]);

    if (!__all(lanemax - m <= 8.0f)) {
        // max grew somewhere in the wave: full row reduce + rescale
        float mx = fmaxf(lanemax, __shfl_xor(lanemax, 16));
        mx = fmaxf(mx, __shfl_xor(mx, 32));
        mx = fmaxf(m, mx);
        const float corr = fexp2(m - mx);
        m = mx;
        l *= corr;
        #pragma unroll
        for (int i = 0; i < 4; i++) { o0[i] *= corr; o1[i] *= corr; }
    }

    float e[16], ls = 0.f;
    #pragma unroll
    for (int i = 0; i < 16; i++) e[i] = fexp2(t16[i] - m);
    if (!interior) {
        // kill exp2(-1e30 - (-1e30)) = 1 for fully-masked rows
        #pragma unroll
        for (int r2 = 0; r2 < 4; r2++) {
            if (!(k0 + r2          < je)) e[r2]      = 0.f;
            if (!(k0 + 4 + r2      < je)) e[4 + r2]  = 0.f;
            if (!(32 + k0 + r2     < je)) e[8 + r2]  = 0.f;
            if (!(32 + k0 + 4 + r2 < je)) e[12 + r2] = 0.f;
        }
    }
    #pragma unroll
    for (int i = 0; i < 16; i++) ls += e[i];
    l += ls;

    union { unsigned u[4]; bf16x8 v; } pbX, pbY;
    pbX.u[0] = pk_bf16(e[0],  e[1]);
    pbX.u[1] = pk_bf16(e[2],  e[3]);
    pbX.u[2] = pk_bf16(e[4],  e[5]);
    pbX.u[3] = pk_bf16(e[6],  e[7]);
    pbY.u[0] = pk_bf16(e[8],  e[9]);
    pbY.u[1] = pk_bf16(e[10], e[11]);
    pbY.u[2] = pk_bf16(e[12], e[13]);
    pbY.u[3] = pk_bf16(e[14], e[15]);

    o0 = MFMA16x16x32(f.v0, pbX.v, o0);
    o1 = MFMA16x16x32(f.v1, pbX.v, o1);
    o0 = MFMA16x16x32(f.v2, pbY.v, o0);
    o1 = MFMA16x16x32(f.v3, pbY.v, o1);
}

// ---------------------------------------------------------------------------
// Kernel 1: gater + gated QKV — R17: 16 tokens per block (was 4). The q/k/v
// weight sweep (48KB/block) is now amortized over 16 tokens: global weight
// traffic 74MB -> 18MB, block count 1536 -> 384. x reads from LDS are
// lane-uniform float4 broadcasts (no bank conflicts). FMA order per token is
// d-ascending exactly as before (absmax-neutral).
// ---------------------------------------------------------------------------
__global__ __launch_bounds__(128) void gate_qkv_kernel(
    const float* __restrict__ x,
    const float* __restrict__ g_ln_w, const float* __restrict__ g_ln_b,
    const float* __restrict__ g_w1,   const float* __restrict__ g_b1,
    const float* __restrict__ g_w2,   const float* __restrict__ g_b2,
    const float* __restrict__ q_w,    const float* __restrict__ q_b,
    const float* __restrict__ k_w,    const float* __restrict__ k_b,
    const float* __restrict__ v_w,    const float* __restrict__ v_b,
    unsigned short* __restrict__ Qh, unsigned short* __restrict__ Ql,
    unsigned short* __restrict__ Kh,
    unsigned short* __restrict__ Vth)
{
    const int tok0 = blockIdx.x * TPB;
    const int tid  = threadIdx.x;

    __shared__ float xs[TPB][DD];
    __shared__ float lns[TPB][DD];
    __shared__ float gate_s[TPB];

    #pragma unroll
    for (int i = 0; i < (TPB * DD) / 128; i++) {
        const int idx = i * 128 + tid;
        xs[idx >> 5][idx & 31] = x[(size_t)tok0 * DD + idx];
    }
    __syncthreads();

    const int tg = tid >> 5;       // token subgroup 0..3
    const int d5 = tid & 31;

    // LayerNorm: 4 tokens per pass (one per 32-lane group), TPB/4 passes
    #pragma unroll
    for (int tt = 0; tt < TPB / 4; tt++) {
        const int t = tt * 4 + tg;
        float xv = xs[t][d5];
        float s1 = xv, s2 = xv * xv;
        #pragma unroll
        for (int mm = 16; mm >= 1; mm >>= 1) {
            s1 += __shfl_xor(s1, mm, 32);
            s2 += __shfl_xor(s2, mm, 32);
        }
        float mu  = s1 * (1.0f / DD);
        float var = s2 * (1.0f / DD) - mu * mu;
        float r   = rsqrtf(var + EPSF);
        lns[t][d5] = (xv - mu) * r * g_ln_w[d5] + g_ln_b[d5];
    }
    __syncthreads();

    // gater hidden + gate scalar (fused: h -> p-reduce in one pass)
    #pragma unroll
    for (int tt = 0; tt < TPB / 4; tt++) {
        const int t = tt * 4 + tg;
        float acc = g_b1[d5];
        #pragma unroll
        for (int d = 0; d < DD; d++) acc += lns[t][d] * g_w1[d * GHH + d5];
        const float h = acc / (1.0f + __expf(-acc));
        float p = h * g_w2[d5];
        #pragma unroll
        for (int mm = 16; mm >= 1; mm >>= 1) p += __shfl_xor(p, mm, 32);
        if (d5 == 0) gate_s[t] = 1.0f / (1.0f + __expf(-(p + g_b2[0])));
    }
    __syncthreads();

    // gated QKV: one output column per thread, 16 tokens deep
    const int col = tid;
    float aq[TPB], ak[TPB], av[TPB];
    {
        const float qb = q_b[col], kb = k_b[col], vb = v_b[col];
        #pragma unroll
        for (int t = 0; t < TPB; t++) { aq[t] = qb; ak[t] = kb; av[t] = vb; }
    }
    for (int d4 = 0; d4 < DD / 4; d4++) {
        float wq[4], wk[4], wv[4];
        #pragma unroll
        for (int j = 0; j < 4; j++) {
            const int d = d4 * 4 + j;
            wq[j] = q_w[d * HIDD + col];
            wk[j] = k_w[d * HIDD + col];
            wv[j] = v_w[d * HIDD + col];
        }
        #pragma unroll
        for (int t = 0; t < TPB; t++) {
            const float4 xv = *reinterpret_cast<const float4*>(&xs[t][d4 * 4]);
            aq[t] += xv.x * wq[0]; aq[t] += xv.y * wq[1];
            aq[t] += xv.z * wq[2]; aq[t] += xv.w * wq[3];
            ak[t] += xv.x * wk[0]; ak[t] += xv.y * wk[1];
            ak[t] += xv.z * wk[2]; ak[t] += xv.w * wk[3];
            av[t] += xv.x * wv[0]; av[t] += xv.y * wv[1];
            av[t] += xv.z * wv[2]; av[t] += xv.w * wv[3];
        }
    }

    const int b    = tok0 / LL;
    const int l0   = tok0 - b * LL;
    const int head = col >> 5;
    const int d5c  = col & 31;
    // 1/sqrt(32) * log2(e) — scores land directly in log2 units.
    const float scale = 0.25503486f;

    union { unsigned short s[TPB]; bf16x8 v8[TPB / 8]; } vh;
    #pragma unroll
    for (int t = 0; t < TPB; t++) {
        const float g = gate_s[t];
        const size_t a = ((size_t)(b * NHH + head) * LL + l0 + t) * HDD + d5c;
        float qv = aq[t] * g * scale;
        unsigned short h = bfh(qv); Qh[a] = h; Ql[a] = bfh(qv - bff(h));
        Kh[a] = bfh(ak[t] * g);
        vh.s[t] = bfh(av[t] * g);
    }
    const size_t vbase = ((size_t)(b * NHH + head) * HDD + d5c) * LL + l0;
    #pragma unroll
    for (int j = 0; j < TPB / 8; j++)
        *reinterpret_cast<bf16x8*>(Vth + vbase + j * 8) = vh.v8[j];
}

// ---------------------------------------------------------------------------
// Kernel 2: MFMA flash-attention partials — LDS-STAGED K/V (R16, proven:
// attn 43.5 -> <42us). Each block stages its full 48KB K/V chunk into LDS
// once (latency paid once, amortized over 4 waves x up to 6 tiles); the tile
// loop reads only LDS. 2-deep frag rotation for ds_read/compute overlap.
// Grid 1-D, bh = blockIdx.x & 7 (XCD-local K/V — R11 verified).
// ---------------------------------------------------------------------------
__global__ __launch_bounds__(256) void attn_mfma(
    const unsigned short* __restrict__ Qh, const unsigned short* __restrict__ Ql,
    const unsigned short* __restrict__ Kh,
    const unsigned short* __restrict__ Vth,
    float* __restrict__ P)
{
    const int lin = blockIdx.x;
    const int bh  = lin & 7;                    // XCD-local clustering
    const int jj  = lin >> 3;
    const int ch  = jj / (LL / 64);
    const int qt  = (LL / 64 - 1) - (jj % (LL / 64));   // heavy prefixes first
    const int j0c = CCH * ch;
    const int jmax_blk = ((qt * 64 + 63) / NF + 1) * NF;
    if (j0c >= jmax_blk) return;           // uniform block exit (pre-barrier)

    __shared__ __align__(16) unsigned short ldsK[CCH * HDD];          // 24576 B
    __shared__ __align__(16) unsigned short ldsV[HDD * (CCH + VPAD)]; // 25088 B

    const int tid = threadIdx.x;

    // ---- stage the FULL chunk (j0c+CCH <= LL always: branchless, static) ----
    {
        const unsigned short* gK = Kh + ((size_t)bh * LL + j0c) * HDD;
        const unsigned short* gV = Vth + (size_t)bh * HDD * LL + j0c;
        const int r  = tid >> 3;        // 0..31 (V dim row)
        const int c8 = tid & 7;         // 0..7  (16B chunk within 64-key group)
        #pragma unroll
        for (int it = 0; it < CCH / 64; it++) {
            const int uk = it * 256 + tid;          // K chunk index
            *reinterpret_cast<bf16x8*>(&ldsK[uk * 8]) = ld8(gK + uk * 8);
            const int off = it * 64 + c8 * 8;       // V elem offset in row
            *reinterpret_cast<bf16x8*>(&ldsV[r * (CCH + VPAD) + off]) =
                ld8(gV + (size_t)r * LL + off);
        }
    }
    __syncthreads();

    const int w    = tid >> 6;
    const int lane = tid & 63;
    const int rr   = lane & 15;            // query row in 16 / V-dim
    const int quad = lane >> 4;

    const int ig0   = qt * 64 + w * 16;
    const int ig    = ig0 + rr;
    const int jend  = (ig / NF + 1) * NF;
    const int jmaxw = ((ig0 + 15) / NF + 1) * NF;
    const int jminw = (ig0 / NF + 1) * NF;

    const int kend = min(jmaxw - j0c, CCH);
    if (kend <= 0) return;                 // dead wave — AFTER the barrier

    const size_t qo = ((size_t)bh * LL + ig) * HDD + quad * 8;
    const bf16x8 qfh = ld8(Qh + qo);
    const bf16x8 qfl = ld8(Ql + qo);

    // permuted local key for A-frag row m=rr: frag f -> key 8*(m>>2)+4f+(m&3)
    const int kloc0 = 8 * (rr >> 2) + (rr & 3);
    const int kloc1 = kloc0 + 4;

    f32x4 o0 = {0.f,0.f,0.f,0.f}, o1 = {0.f,0.f,0.f,0.f};
    float m = -1e30f, l = 0.f;

    const int ntile = (kend + 63) >> 6;    // 1..6

    // 2-deep frag rotation: next tile's ds_reads issue under current compute.
    Frags f0;
    load_tile_lds(ldsK, ldsV, 0, kloc0, kloc1, quad, rr, f0);
    for (int i = 0; i < ntile; i++) {
        const int j0 = j0c + (i << 6);
        if (i + 1 < ntile) {
            Frags f1;
            load_tile_lds(ldsK, ldsV, (i + 1) << 6, kloc0, kloc1, quad, rr, f1);
            compute_tile(f0, qfh, qfl, j0, jminw, jend, quad, m, l, o0, o1);
            f0 = f1;
        } else {
            compute_tile(f0, qfh, qfl, j0, jminw, jend, quad, m, l, o0, o1);
        }
    }

    // l holds only this lane's partials; quads share the same m scale, so the
    // row denominator is the cross-quad sum (R8 bug fix).
    l += __shfl_xor(l, 16);
    l += __shfl_xor(l, 32);

    // write chunk partial: P[bh][qt16][ch][row16][36]  (m in log2 units)
    float* dst = P + ((((size_t)bh * NQT16 + (ig0 >> 4)) * NCHC + ch) * 16 + rr) * 36;
    *(f32x4*)(dst + quad * 4)      = o0;   // dims quad*4 .. +3
    *(f32x4*)(dst + 16 + quad * 4) = o1;   // dims 16+quad*4 .. +3
    if (quad == 0) { dst[32] = m; dst[33] = l; }
}

// ---------------------------------------------------------------------------
// Kernel 3: chunk-merge (flash-decoding, exp2 domain) + mean-pool + o-proj
// + LN + f-proj + SiLU. Block per (t, b), 128 threads. R17: the two
// 128-deep projection loops use 4 independent accumulator chains (was one
// dependent FMA chain each — latency-bound at 2 waves/block).
// ---------------------------------------------------------------------------
__global__ __launch_bounds__(128) void final_kernel(
    const float* __restrict__ P,
    const float* __restrict__ o_w,    const float* __restrict__ o_b,
    const float* __restrict__ f_ln_w, const float* __restrict__ f_ln_b,
    const float* __restrict__ f_w,    const float* __restrict__ f_b,
    float* __restrict__ out, int C, int NCH)
{
    const int t = blockIdx.x;
    const int b = blockIdx.y;
    const int d = threadIdx.x;     // 0..127
    const int h  = d >> 5;         // head
    const int hd = d & 31;         // dim within head
    const int bh = b * NHH + h;

    __shared__ float ms[HIDD];
    __shared__ float lnbuf[HIDD];
    __shared__ float w1[2], w2[2];

    const int jmax = (t + 1) * NF;
    const int nch  = min(NCH, (jmax + C - 1) / C);

    float M[NF], L[NF], O[NF];
    #pragma unroll
    for (int f = 0; f < NF; f++) { M[f] = -1e30f; L[f] = 0.f; O[f] = 0.f; }

    for (int c = 0; c < nch; c++) {
        #pragma unroll
        for (int f = 0; f < NF; f++) {
            const int row = t * NF + f;
            const float* pr = P + ((((size_t)bh * NQT16 + (row >> 4)) * NCH + c)
                                   * 16 + (row & 15)) * 36;
            const float mc = pr[32], lc = pr[33], oc = pr[hd];
            const float mm = fmaxf(M[f], mc);
            const float sa = fexp2(M[f] - mm), sb = fexp2(mc - mm);
            O[f] = O[f] * sa + oc * sb;
            L[f] = L[f] * sa + lc * sb;
            M[f] = mm;
        }
    }
    float acc = 0.0f;
    #pragma unroll
    for (int f = 0; f < NF; f++) acc += O[f] / L[f];
    acc *= (1.0f / NF);
    ms[d] = acc;
    __syncthreads();

    float ov0 = 0.f, ov1 = 0.f, ov2 = 0.f, ov3 = 0.f;
    for (int k = 0; k < HIDD; k += 4) {
        ov0 += ms[k]     * o_w[(k)     * HIDD + d];
        ov1 += ms[k + 1] * o_w[(k + 1) * HIDD + d];
        ov2 += ms[k + 2] * o_w[(k + 2) * HIDD + d];
        ov3 += ms[k + 3] * o_w[(k + 3) * HIDD + d];
    }
    float ov = o_b[d] + ((ov0 + ov1) + (ov2 + ov3));

    float s1 = ov, s2 = ov * ov;
    #pragma unroll
    for (int m = 32; m >= 1; m >>= 1) { s1 += __shfl_xor(s1, m); s2 += __shfl_xor(s2, m); }
    if ((d & 63) == 0) { w1[d >> 6] = s1; w2[d >> 6] = s2; }
    __syncthreads();
    float S1 = w1[0] + w1[1], S2 = w2[0] + w2[1];
    float mu  = S1 * (1.0f / HIDD);
    float var = S2 * (1.0f / HIDD) - mu * mu;
    float r   = rsqrtf(var + EPSF);
    float lnv = (ov - mu) * r * f_ln_w[d] + f_ln_b[d];
    lnbuf[d] = lnv;
    __syncthreads();

    float fv0 = 0.f, fv1 = 0.f, fv2 = 0.f, fv3 = 0.f;
    for (int k = 0; k < HIDD; k += 4) {
        fv0 += lnbuf[k]     * f_w[(k)     * HIDD + d];
        fv1 += lnbuf[k + 1] * f_w[(k + 1) * HIDD + d];
        fv2 += lnbuf[k + 2] * f_w[(k + 2) * HIDD + d];
        fv3 += lnbuf[k + 3] * f_w[(k + 3) * HIDD + d];
    }
    float fv = f_b[d] + ((fv0 + fv1) + (fv2 + fv3));
    fv = fv / (1.0f + __expf(-fv));

    out[((size_t)(b * TT + t)) * FDD + d] = fv;
}

// ---------------------------------------------------------------------------
extern "C" void kernel_launch(void* const* d_in, const int* in_sizes, int n_in,
                              void* d_out, int out_size, void* d_ws, size_t ws_size,
                              hipStream_t stream)
{
    const float* x      = (const float*)d_in[0];
    const float* g_ln_w = (const float*)d_in[1];
    const float* g_ln_b = (const float*)d_in[2];
    const float* g_w1   = (const float*)d_in[3];
    const float* g_b1   = (const float*)d_in[4];
    const float* g_w2   = (const float*)d_in[5];
    const float* g_b2   = (const float*)d_in[6];
    const float* q_w    = (const float*)d_in[7];
    const float* q_b    = (const float*)d_in[8];
    const float* k_w    = (const float*)d_in[9];
    const float* k_b    = (const float*)d_in[10];
    const float* v_w    = (const float*)d_in[11];
    const float* v_b    = (const float*)d_in[12];
    const float* o_w    = (const float*)d_in[13];
    const float* o_b    = (const float*)d_in[14];
    const float* f_ln_w = (const float*)d_in[15];
    const float* f_ln_b = (const float*)d_in[16];
    const float* f_w    = (const float*)d_in[17];
    const float* f_b    = (const float*)d_in[18];

    const size_t ntok = (size_t)BB * NHH * LL * HDD;     // 786432 bf16 elems/array
    unsigned short* Qh  = (unsigned short*)d_ws;
    unsigned short* Ql  = Qh  + ntok;
    unsigned short* Kh  = Ql  + ntok;
    // region [Kh+ntok, Kh+2*ntok) reserved (was Kl) — layout kept identical
    unsigned short* Vth = Kh + 2 * ntok;
    // region [Vth+ntok, Vth+2*ntok) reserved (was Vtl)
    float* Pw = (float*)(Vth + 2 * ntok);                // split-K partials

    gate_qkv_kernel<<<(BB * LL) / TPB, 128, 0, stream>>>(
        x, g_ln_w, g_ln_b, g_w1, g_b1, g_w2, g_b2,
        q_w, q_b, k_w, k_b, v_w, v_b, Qh, Ql, Kh, Vth);

    attn_mfma<<<(LL / 64) * NCHC * BB * NHH, 256, 0, stream>>>(
        Qh, Ql, Kh, Vth, Pw);

    final_kernel<<<dim3(TT, BB), 128, 0, stream>>>(
        Pw, o_w, o_b, f_ln_w, f_ln_b, f_w, f_b, (float*)d_out, CCH, NCHC);
}

// Round 5
// 140.287 us; speedup vs baseline: 1.0014x; 1.0014x over previous
//
#include <hip/hip_runtime.h>
#include <hip/hip_bf16.h>

#define BB   2
#define TT   512
#define NF   6
#define DD   32
#define HIDD 128
#define NHH  4
#define HDD  32
#define GHH  32
#define FDD  128
#define LL   (TT*NF)      // 3072
#define EPSF 1e-5f
#define NQT16 (LL/16)     // 192

// Split-K geometry (compile-time; NCH=16 regressed in R15 — stay at 8).
#define NCHC 8
#define CCH  384          // keys per chunk = 6 tiles of 64
#define VPAD 8            // ldsV row padding: keeps 16B alignment; 8 lanes/bank = b128 floor
#define NQP  (LL/128)     // 24 q-tile PAIRS (R18)

// R17: gate_qkv tokens per block.
#define TPB  16

typedef __attribute__((ext_vector_type(8))) short  bf16x8;
typedef __attribute__((ext_vector_type(4))) float  f32x4;

#define MFMA16x16x32(a,b,c) __builtin_amdgcn_mfma_f32_16x16x32_bf16(a,b,c,0,0,0)

__device__ __forceinline__ unsigned short bfh(float f) {
    union { __hip_bfloat16 b; unsigned short u; } cv;
    cv.b = __float2bfloat16(f);
    return cv.u;
}
__device__ __forceinline__ float bff(unsigned short u) {
    return __uint_as_float(((unsigned)u) << 16);
}
__device__ __forceinline__ unsigned pk_bf16(float a, float b) {
    union { __hip_bfloat162 h2; unsigned u; } cv;
    cv.h2 = __float22bfloat162_rn(make_float2(a, b));
    return cv.u;
}
__device__ __forceinline__ bf16x8 ld8(const unsigned short* p) {
    return *reinterpret_cast<const bf16x8*>(p);
}

// exp2-domain softmax (log2e folded into Q scale) — R15, kept.
__device__ __forceinline__ float fexp2(float x) {
#if __has_builtin(__builtin_amdgcn_exp2f)
    return __builtin_amdgcn_exp2f(x);
#else
    return exp2f(x);
#endif
}

// 8 frags per 64-key tile (K-lo / V-lo splits dropped — R13/R14 verified).
struct Frags {
    bf16x8 k0, k1;   // keys X = [j0, j0+32), frag rows 0/1
    bf16x8 k2, k3;   // keys Y = [j0+32, j0+64)
    bf16x8 v0, v1, v2, v3;   // V^T hi: (dims rr / rr+16) x (X / Y)
};

// R16: frags come from LDS (latency-immune) instead of global/L2.
__device__ __forceinline__ void load_tile_lds(
    const unsigned short* ldsK, const unsigned short* ldsV,
    int j0loc, int kloc0, int kloc1, int quad, int rr, Frags& f)
{
    const int kX0 = (j0loc + kloc0) * HDD + quad * 8;
    const int kX1 = (j0loc + kloc1) * HDD + quad * 8;
    f.k0 = ld8(ldsK + kX0);
    f.k1 = ld8(ldsK + kX1);
    f.k2 = ld8(ldsK + kX0 + 32 * HDD);
    f.k3 = ld8(ldsK + kX1 + 32 * HDD);
    const int vX = j0loc + quad * 8, vY = vX + 32;
    const int vr0 = rr * (CCH + VPAD), vr1 = (rr + 16) * (CCH + VPAD);
    f.v0 = ld8(ldsV + vr0 + vX);
    f.v1 = ld8(ldsV + vr1 + vX);
    f.v2 = ld8(ldsV + vr0 + vY);
    f.v3 = ld8(ldsV + vr1 + vY);
}

// One tile's scores + online softmax + PV, updating (m, l, o0, o1).
// Scores/m are in log2 units (Q pre-scaled by log2e/sqrt(HD)).
// R17: defer-max (T13) — wave-uniform __all(lanemax - m <= 8) skips the
// cross-quad reduce + rescale on tiles whose max doesn't grow.
__device__ __forceinline__ void compute_tile(
    const Frags& f, const bf16x8 qfh, const bf16x8 qfl,
    int j0, int jminw, int jend, int quad,
    float& m, float& l, f32x4& o0, f32x4& o1)
{
    const f32x4 z = {0.f, 0.f, 0.f, 0.f};
    f32x4 s0 = MFMA16x16x32(f.k0, qfh, z);
    f32x4 s1 = MFMA16x16x32(f.k1, qfh, z);
    f32x4 s2 = MFMA16x16x32(f.k2, qfh, z);
    f32x4 s3 = MFMA16x16x32(f.k3, qfh, z);
    s0 = MFMA16x16x32(f.k0, qfl, s0);
    s1 = MFMA16x16x32(f.k1, qfl, s1);
    s2 = MFMA16x16x32(f.k2, qfl, s2);
    s3 = MFMA16x16x32(f.k3, qfl, s3);

    const bool interior = (j0 + 64 <= jminw);   // wave-uniform
    const int  je = jend - j0;
    const int  k0 = 8 * quad;

    float t16[16];
    if (interior) {
        #pragma unroll
        for (int r2 = 0; r2 < 4; r2++) {
            t16[r2]      = s0[r2];
            t16[4 + r2]  = s1[r2];
            t16[8 + r2]  = s2[r2];
            t16[12 + r2] = s3[r2];
        }
    } else {
        #pragma unroll
        for (int r2 = 0; r2 < 4; r2++) {
            t16[r2]      = (k0 + r2          < je) ? s0[r2] : -1e30f;
            t16[4 + r2]  = (k0 + 4 + r2      < je) ? s1[r2] : -1e30f;
            t16[8 + r2]  = (32 + k0 + r2     < je) ? s2[r2] : -1e30f;
            t16[12 + r2] = (32 + k0 + 4 + r2 < je) ? s3[r2] : -1e30f;
        }
    }

    // lane-local max (15 ops)
    float lanemax = t16[0];
    #pragma unroll
    for (int i = 1; i < 16; i++) lanemax = fmaxf(lanemax, t16[i]);

    if (!__all(lanemax - m <= 8.0f)) {
        // max grew somewhere in the wave: full row reduce + rescale
        float mx = fmaxf(lanemax, __shfl_xor(lanemax, 16));
        mx = fmaxf(mx, __shfl_xor(mx, 32));
        mx = fmaxf(m, mx);
        const float corr = fexp2(m - mx);
        m = mx;
        l *= corr;
        #pragma unroll
        for (int i = 0; i < 4; i++) { o0[i] *= corr; o1[i] *= corr; }
    }

    float e[16], ls = 0.f;
    #pragma unroll
    for (int i = 0; i < 16; i++) e[i] = fexp2(t16[i] - m);
    if (!interior) {
        // kill exp2(-1e30 - (-1e30)) = 1 for fully-masked rows
        #pragma unroll
        for (int r2 = 0; r2 < 4; r2++) {
            if (!(k0 + r2          < je)) e[r2]      = 0.f;
            if (!(k0 + 4 + r2      < je)) e[4 + r2]  = 0.f;
            if (!(32 + k0 + r2     < je)) e[8 + r2]  = 0.f;
            if (!(32 + k0 + 4 + r2 < je)) e[12 + r2] = 0.f;
        }
    }
    #pragma unroll
    for (int i = 0; i < 16; i++) ls += e[i];
    l += ls;

    union { unsigned u[4]; bf16x8 v; } pbX, pbY;
    pbX.u[0] = pk_bf16(e[0],  e[1]);
    pbX.u[1] = pk_bf16(e[2],  e[3]);
    pbX.u[2] = pk_bf16(e[4],  e[5]);
    pbX.u[3] = pk_bf16(e[6],  e[7]);
    pbY.u[0] = pk_bf16(e[8],  e[9]);
    pbY.u[1] = pk_bf16(e[10], e[11]);
    pbY.u[2] = pk_bf16(e[12], e[13]);
    pbY.u[3] = pk_bf16(e[14], e[15]);

    o0 = MFMA16x16x32(f.v0, pbX.v, o0);
    o1 = MFMA16x16x32(f.v1, pbX.v, o1);
    o0 = MFMA16x16x32(f.v2, pbY.v, o0);
    o1 = MFMA16x16x32(f.v3, pbY.v, o1);
}

// ---------------------------------------------------------------------------
// Kernel 1: gater + gated QKV (R17 form, measured-neutral — frozen).
// ---------------------------------------------------------------------------
__global__ __launch_bounds__(128) void gate_qkv_kernel(
    const float* __restrict__ x,
    const float* __restrict__ g_ln_w, const float* __restrict__ g_ln_b,
    const float* __restrict__ g_w1,   const float* __restrict__ g_b1,
    const float* __restrict__ g_w2,   const float* __restrict__ g_b2,
    const float* __restrict__ q_w,    const float* __restrict__ q_b,
    const float* __restrict__ k_w,    const float* __restrict__ k_b,
    const float* __restrict__ v_w,    const float* __restrict__ v_b,
    unsigned short* __restrict__ Qh, unsigned short* __restrict__ Ql,
    unsigned short* __restrict__ Kh,
    unsigned short* __restrict__ Vth)
{
    const int tok0 = blockIdx.x * TPB;
    const int tid  = threadIdx.x;

    __shared__ float xs[TPB][DD];
    __shared__ float lns[TPB][DD];
    __shared__ float gate_s[TPB];

    #pragma unroll
    for (int i = 0; i < (TPB * DD) / 128; i++) {
        const int idx = i * 128 + tid;
        xs[idx >> 5][idx & 31] = x[(size_t)tok0 * DD + idx];
    }
    __syncthreads();

    const int tg = tid >> 5;       // token subgroup 0..3
    const int d5 = tid & 31;

    #pragma unroll
    for (int tt = 0; tt < TPB / 4; tt++) {
        const int t = tt * 4 + tg;
        float xv = xs[t][d5];
        float s1 = xv, s2 = xv * xv;
        #pragma unroll
        for (int mm = 16; mm >= 1; mm >>= 1) {
            s1 += __shfl_xor(s1, mm, 32);
            s2 += __shfl_xor(s2, mm, 32);
        }
        float mu  = s1 * (1.0f / DD);
        float var = s2 * (1.0f / DD) - mu * mu;
        float r   = rsqrtf(var + EPSF);
        lns[t][d5] = (xv - mu) * r * g_ln_w[d5] + g_ln_b[d5];
    }
    __syncthreads();

    #pragma unroll
    for (int tt = 0; tt < TPB / 4; tt++) {
        const int t = tt * 4 + tg;
        float acc = g_b1[d5];
        #pragma unroll
        for (int d = 0; d < DD; d++) acc += lns[t][d] * g_w1[d * GHH + d5];
        const float h = acc / (1.0f + __expf(-acc));
        float p = h * g_w2[d5];
        #pragma unroll
        for (int mm = 16; mm >= 1; mm >>= 1) p += __shfl_xor(p, mm, 32);
        if (d5 == 0) gate_s[t] = 1.0f / (1.0f + __expf(-(p + g_b2[0])));
    }
    __syncthreads();

    const int col = tid;
    float aq[TPB], ak[TPB], av[TPB];
    {
        const float qb = q_b[col], kb = k_b[col], vb = v_b[col];
        #pragma unroll
        for (int t = 0; t < TPB; t++) { aq[t] = qb; ak[t] = kb; av[t] = vb; }
    }
    for (int d4 = 0; d4 < DD / 4; d4++) {
        float wq[4], wk[4], wv[4];
        #pragma unroll
        for (int j = 0; j < 4; j++) {
            const int d = d4 * 4 + j;
            wq[j] = q_w[d * HIDD + col];
            wk[j] = k_w[d * HIDD + col];
            wv[j] = v_w[d * HIDD + col];
        }
        #pragma unroll
        for (int t = 0; t < TPB; t++) {
            const float4 xv = *reinterpret_cast<const float4*>(&xs[t][d4 * 4]);
            aq[t] += xv.x * wq[0]; aq[t] += xv.y * wq[1];
            aq[t] += xv.z * wq[2]; aq[t] += xv.w * wq[3];
            ak[t] += xv.x * wk[0]; ak[t] += xv.y * wk[1];
            ak[t] += xv.z * wk[2]; ak[t] += xv.w * wk[3];
            av[t] += xv.x * wv[0]; av[t] += xv.y * wv[1];
            av[t] += xv.z * wv[2]; av[t] += xv.w * wv[3];
        }
    }

    const int b    = tok0 / LL;
    const int l0   = tok0 - b * LL;
    const int head = col >> 5;
    const int d5c  = col & 31;
    // 1/sqrt(32) * log2(e) — scores land directly in log2 units.
    const float scale = 0.25503486f;

    union { unsigned short s[TPB]; bf16x8 v8[TPB / 8]; } vh;
    #pragma unroll
    for (int t = 0; t < TPB; t++) {
        const float g = gate_s[t];
        const size_t a = ((size_t)(b * NHH + head) * LL + l0 + t) * HDD + d5c;
        float qv = aq[t] * g * scale;
        unsigned short h = bfh(qv); Qh[a] = h; Ql[a] = bfh(qv - bff(h));
        Kh[a] = bfh(ak[t] * g);
        vh.s[t] = bfh(av[t] * g);
    }
    const size_t vbase = ((size_t)(b * NHH + head) * HDD + d5c) * LL + l0;
    #pragma unroll
    for (int j = 0; j < TPB / 8; j++)
        *reinterpret_cast<bf16x8*>(Vth + vbase + j * 8) = vh.v8[j];
}

// ---------------------------------------------------------------------------
// Kernel 2: MFMA flash-attention partials — R18 (resubmitted after infra
// failure): 8-WAVE BLOCKS, q-tile PAIR per block. R16 proved the loop must
// be LDS-fed; R17/R15 proved wave-count alone is not the lever. Remaining
// slack: residency was LDS-capped at 3 blocks/CU (12 waves/CU, vs 16
// VGPR-allowed) and every 48KB chunk was staged once per 64 q-rows. Now 8
// waves (128 q-rows = one qt pair) share one staged chunk: waves/CU 12->16,
// staged traffic 77->38MB, blocks and barriers halve. Per-wave work/chain
// unchanged. P layout, final, gate untouched — single-variable probe.
// Grid 1-D, bh = blockIdx.x & 7 (XCD-local K/V — R11 verified).
// ---------------------------------------------------------------------------
__global__ __launch_bounds__(512) void attn_mfma(
    const unsigned short* __restrict__ Qh, const unsigned short* __restrict__ Ql,
    const unsigned short* __restrict__ Kh,
    const unsigned short* __restrict__ Vth,
    float* __restrict__ P)
{
    const int lin = blockIdx.x;
    const int bh  = lin & 7;                    // XCD-local clustering
    const int jj  = lin >> 3;
    const int ch  = jj / NQP;
    const int qp  = (NQP - 1) - (jj % NQP);     // heavy prefixes first
    const int j0c = CCH * ch;
    const int jmax_blk = ((qp * 128 + 127) / NF + 1) * NF;
    if (j0c >= jmax_blk) return;           // uniform block exit (pre-barrier)

    __shared__ __align__(16) unsigned short ldsK[CCH * HDD];          // 24576 B
    __shared__ __align__(16) unsigned short ldsV[HDD * (CCH + VPAD)]; // 25088 B

    const int tid = threadIdx.x;

    // ---- stage the FULL chunk (j0c+CCH <= LL always: branchless, static) ----
    {
        const unsigned short* gK = Kh + ((size_t)bh * LL + j0c) * HDD;
        const unsigned short* gV = Vth + (size_t)bh * HDD * LL + j0c;
        const int r   = tid >> 4;       // 0..31 (V dim row), 16 threads/row
        const int c16 = tid & 15;       // 16B chunk group within row
        #pragma unroll
        for (int it = 0; it < 3; it++) {
            const int uk = it * 512 + tid;          // K 16B-chunk 0..1535
            *reinterpret_cast<bf16x8*>(&ldsK[uk * 8]) = ld8(gK + uk * 8);
            const int off = (c16 + it * 16) * 8;    // V elem offset in row
            *reinterpret_cast<bf16x8*>(&ldsV[r * (CCH + VPAD) + off]) =
                ld8(gV + (size_t)r * LL + off);
        }
    }
    __syncthreads();

    const int w    = tid >> 6;             // 0..7: q sub-tile within the pair
    const int lane = tid & 63;
    const int rr   = lane & 15;            // query row in 16 / V-dim
    const int quad = lane >> 4;

    const int ig0   = qp * 128 + w * 16;
    const int ig    = ig0 + rr;
    const int jend  = (ig / NF + 1) * NF;
    const int jmaxw = ((ig0 + 15) / NF + 1) * NF;
    const int jminw = (ig0 / NF + 1) * NF;

    const int kend = min(jmaxw - j0c, CCH);
    if (kend <= 0) return;                 // dead wave — AFTER the barrier

    const size_t qo = ((size_t)bh * LL + ig) * HDD + quad * 8;
    const bf16x8 qfh = ld8(Qh + qo);
    const bf16x8 qfl = ld8(Ql + qo);

    // permuted local key for A-frag row m=rr: frag f -> key 8*(m>>2)+4f+(m&3)
    const int kloc0 = 8 * (rr >> 2) + (rr & 3);
    const int kloc1 = kloc0 + 4;

    f32x4 o0 = {0.f,0.f,0.f,0.f}, o1 = {0.f,0.f,0.f,0.f};
    float m = -1e30f, l = 0.f;

    const int ntile = (kend + 63) >> 6;    // 1..6

    // 2-deep frag rotation: next tile's ds_reads issue under current compute.
    Frags f0;
    load_tile_lds(ldsK, ldsV, 0, kloc0, kloc1, quad, rr, f0);
    for (int i = 0; i < ntile; i++) {
        const int j0 = j0c + (i << 6);
        if (i + 1 < ntile) {
            Frags f1;
            load_tile_lds(ldsK, ldsV, (i + 1) << 6, kloc0, kloc1, quad, rr, f1);
            compute_tile(f0, qfh, qfl, j0, jminw, jend, quad, m, l, o0, o1);
            f0 = f1;
        } else {
            compute_tile(f0, qfh, qfl, j0, jminw, jend, quad, m, l, o0, o1);
        }
    }

    // l holds only this lane's partials; quads share the same m scale, so the
    // row denominator is the cross-quad sum (R8 bug fix).
    l += __shfl_xor(l, 16);
    l += __shfl_xor(l, 32);

    // write chunk partial: P[bh][qt16][ch][row16][36]  (m in log2 units)
    float* dst = P + ((((size_t)bh * NQT16 + (ig0 >> 4)) * NCHC + ch) * 16 + rr) * 36;
    *(f32x4*)(dst + quad * 4)      = o0;   // dims quad*4 .. +3
    *(f32x4*)(dst + 16 + quad * 4) = o1;   // dims 16+quad*4 .. +3
    if (quad == 0) { dst[32] = m; dst[33] = l; }
}

// ---------------------------------------------------------------------------
// Kernel 3: chunk-merge + mean-pool + o-proj + LN + f-proj + SiLU
// (R17 form, frozen).
// ---------------------------------------------------------------------------
__global__ __launch_bounds__(128) void final_kernel(
    const float* __restrict__ P,
    const float* __restrict__ o_w,    const float* __restrict__ o_b,
    const float* __restrict__ f_ln_w, const float* __restrict__ f_ln_b,
    const float* __restrict__ f_w,    const float* __restrict__ f_b,
    float* __restrict__ out, int C, int NCH)
{
    const int t = blockIdx.x;
    const int b = blockIdx.y;
    const int d = threadIdx.x;     // 0..127
    const int h  = d >> 5;         // head
    const int hd = d & 31;         // dim within head
    const int bh = b * NHH + h;

    __shared__ float ms[HIDD];
    __shared__ float lnbuf[HIDD];
    __shared__ float w1[2], w2[2];

    const int jmax = (t + 1) * NF;
    const int nch  = min(NCH, (jmax + C - 1) / C);

    float M[NF], L[NF], O[NF];
    #pragma unroll
    for (int f = 0; f < NF; f++) { M[f] = -1e30f; L[f] = 0.f; O[f] = 0.f; }

    for (int c = 0; c < nch; c++) {
        #pragma unroll
        for (int f = 0; f < NF; f++) {
            const int row = t * NF + f;
            const float* pr = P + ((((size_t)bh * NQT16 + (row >> 4)) * NCH + c)
                                   * 16 + (row & 15)) * 36;
            const float mc = pr[32], lc = pr[33], oc = pr[hd];
            const float mm = fmaxf(M[f], mc);
            const float sa = fexp2(M[f] - mm), sb = fexp2(mc - mm);
            O[f] = O[f] * sa + oc * sb;
            L[f] = L[f] * sa + lc * sb;
            M[f] = mm;
        }
    }
    float acc = 0.0f;
    #pragma unroll
    for (int f = 0; f < NF; f++) acc += O[f] / L[f];
    acc *= (1.0f / NF);
    ms[d] = acc;
    __syncthreads();

    float ov0 = 0.f, ov1 = 0.f, ov2 = 0.f, ov3 = 0.f;
    for (int k = 0; k < HIDD; k += 4) {
        ov0 += ms[k]     * o_w[(k)     * HIDD + d];
        ov1 += ms[k + 1] * o_w[(k + 1) * HIDD + d];
        ov2 += ms[k + 2] * o_w[(k + 2) * HIDD + d];
        ov3 += ms[k + 3] * o_w[(k + 3) * HIDD + d];
    }
    float ov = o_b[d] + ((ov0 + ov1) + (ov2 + ov3));

    float s1 = ov, s2 = ov * ov;
    #pragma unroll
    for (int m = 32; m >= 1; m >>= 1) { s1 += __shfl_xor(s1, m); s2 += __shfl_xor(s2, m); }
    if ((d & 63) == 0) { w1[d >> 6] = s1; w2[d >> 6] = s2; }
    __syncthreads();
    float S1 = w1[0] + w1[1], S2 = w2[0] + w2[1];
    float mu  = S1 * (1.0f / HIDD);
    float var = S2 * (1.0f / HIDD) - mu * mu;
    float r   = rsqrtf(var + EPSF);
    float lnv = (ov - mu) * r * f_ln_w[d] + f_ln_b[d];
    lnbuf[d] = lnv;
    __syncthreads();

    float fv0 = 0.f, fv1 = 0.f, fv2 = 0.f, fv3 = 0.f;
    for (int k = 0; k < HIDD; k += 4) {
        fv0 += lnbuf[k]     * f_w[(k)     * HIDD + d];
        fv1 += lnbuf[k + 1] * f_w[(k + 1) * HIDD + d];
        fv2 += lnbuf[k + 2] * f_w[(k + 2) * HIDD + d];
        fv3 += lnbuf[k + 3] * f_w[(k + 3) * HIDD + d];
    }
    float fv = f_b[d] + ((fv0 + fv1) + (fv2 + fv3));
    fv = fv / (1.0f + __expf(-fv));

    out[((size_t)(b * TT + t)) * FDD + d] = fv;
}

// ---------------------------------------------------------------------------
extern "C" void kernel_launch(void* const* d_in, const int* in_sizes, int n_in,
                              void* d_out, int out_size, void* d_ws, size_t ws_size,
                              hipStream_t stream)
{
    const float* x      = (const float*)d_in[0];
    const float* g_ln_w = (const float*)d_in[1];
    const float* g_ln_b = (const float*)d_in[2];
    const float* g_w1   = (const float*)d_in[3];
    const float* g_b1   = (const float*)d_in[4];
    const float* g_w2   = (const float*)d_in[5];
    const float* g_b2   = (const float*)d_in[6];
    const float* q_w    = (const float*)d_in[7];
    const float* q_b    = (const float*)d_in[8];
    const float* k_w    = (const float*)d_in[9];
    const float* k_b    = (const float*)d_in[10];
    const float* v_w    = (const float*)d_in[11];
    const float* v_b    = (const float*)d_in[12];
    const float* o_w    = (const float*)d_in[13];
    const float* o_b    = (const float*)d_in[14];
    const float* f_ln_w = (const float*)d_in[15];
    const float* f_ln_b = (const float*)d_in[16];
    const float* f_w    = (const float*)d_in[17];
    const float* f_b    = (const float*)d_in[18];

    const size_t ntok = (size_t)BB * NHH * LL * HDD;     // 786432 bf16 elems/array
    unsigned short* Qh  = (unsigned short*)d_ws;
    unsigned short* Ql  = Qh  + ntok;
    unsigned short* Kh  = Ql  + ntok;
    // region [Kh+ntok, Kh+2*ntok) reserved (was Kl) — layout kept identical
    unsigned short* Vth = Kh + 2 * ntok;
    // region [Vth+ntok, Vth+2*ntok) reserved (was Vtl)
    float* Pw = (float*)(Vth + 2 * ntok);                // split-K partials

    gate_qkv_kernel<<<(BB * LL) / TPB, 128, 0, stream>>>(
        x, g_ln_w, g_ln_b, g_w1, g_b1, g_w2, g_b2,
        q_w, q_b, k_w, k_b, v_w, v_b, Qh, Ql, Kh, Vth);

    attn_mfma<<<NQP * NCHC * BB * NHH, 512, 0, stream>>>(
        Qh, Ql, Kh, Vth, Pw);

    final_kernel<<<dim3(TT, BB), 128, 0, stream>>>(
        Pw, o_w, o_b, f_ln_w, f_ln_b, f_w, f_b, (float*)d_out, CCH, NCHC);
}